// Round 12
// baseline (622.452 us; speedup 1.0000x reference)
//
#include <hip/hip_runtime.h>
#include <math.h>

// Problem constants (reference: B=8, C=32, O=32, H=256, W=256, K=5, pad=2)
constexpr int IMG_H = 256;
constexpr int IMG_W = 256;
constexpr int NB = 8;
constexpr int NC = 32;
constexpr int NO = 32;
constexpr int PLANE = IMG_H * IMG_W;          // 65536
constexpr int HALF = NB * NC * PLANE;         // 16,777,216 floats (64 MB)

// Fused tiling, output-split: block = one (b, 16x16 tile), 512 threads.
// Thread t -> pixel t>>1, output half og = t&1 (16 outputs each).
// Channels streamed 4 per barrier phase through 8 LDS buffers (2 sets).
constexpr int TW = 16;                        // tile width
constexpr int TH = 16;                        // tile height
constexpr int NT = 512;                       // threads (2 per pixel)
constexpr int RR = 20;                        // region rows (halo 2)
constexpr int RC = 24;                        // stored cols [w0-4, w0+20)
constexpr int RSB = RC * 8;                   // 192 B row stride ({P,V} f2/px)
constexpr int BUFB = RR * RSB;                // 3840 B per channel buffer
constexpr int NTASK = RR * 12;                // 240 staging tasks per channel
constexpr int CHPH = 4;                       // channels per phase
constexpr int TPH = CHPH * NTASK;             // 960 tasks per phase
constexpr int TILES = (IMG_W / TW) * (IMG_H / TH);  // 256 tiles per image
constexpr int NBLK = TILES * NB;              // 2048 blocks

#define EPSV 1e-20f

typedef float f4 __attribute__((ext_vector_type(4)));
typedef float f2 __attribute__((ext_vector_type(2)));

__device__ __forceinline__ float rcpf_(float x) { return __builtin_amdgcn_rcpf(x); }
__device__ __forceinline__ float softplusf_(float x) {
  return fmaxf(x, 0.0f) + log1pf(expf(-fabsf(x)));
}

// ws layout (floats): [0..31] wp, [32..831] sw (c-major, 25/ch),
// [832..1855] cwT[c][o] (transposed), [1856] sum(sw), [1857] sum(cw)
__global__ void weights_kernel(const float* __restrict__ wp_raw,
                               const float* __restrict__ sw_raw,
                               const float* __restrict__ cw_raw,
                               float* __restrict__ ws) {
  __shared__ float red[256];
  const int t = threadIdx.x;
  if (t < 32) ws[t] = softplusf_(wp_raw[t]);
  float ssum = 0.f;
  for (int i = t; i < NC * 25; i += 256) {
    float v = softplusf_(sw_raw[i]);
    ws[32 + i] = v;
    ssum += v;
  }
  float csum = 0.f;
  for (int i = t; i < NO * NC; i += 256) {
    float v = softplusf_(cw_raw[i]);
    int o = i >> 5, c = i & 31;
    ws[832 + c * NO + o] = v;  // transposed: [c][o]
    csum += v;
  }
  red[t] = ssum; __syncthreads();
  for (int off = 128; off; off >>= 1) { if (t < off) red[t] += red[t + off]; __syncthreads(); }
  const float S_sw = red[0];
  __syncthreads();
  red[t] = csum; __syncthreads();
  for (int off = 128; off; off >>= 1) { if (t < off) red[t] += red[t + off]; __syncthreads(); }
  if (t == 0) { ws[1856] = S_sw; ws[1857] = red[0]; }
}

// Pointwise gradient-propagation math. Requires cdv/cgv pre-zeroed for
// OOB pixels (then Pv = Vv = 0 algebraically, no NaN).
// P = den*inv_wp1; V = num*inv_wp1 (den/(den+eps) == 1 to fp32 unless
// den < 1e-13, where |num| <= den*O(1) anyway; den=0 => num=0 => V=0).
// All rcp arguments >= EPSV (R9 lesson: no rcp(0)=inf path).
__device__ __forceinline__ void pointwise_pv(
    float dv, float cdv, float gxv, float cgv, int gw,
    float wpc, float inv_wp1, float& Pv, float& Vv) {
  float dl  = (gw == IMG_W - 1) ? 0.f : dv;
  float cdl = (gw == IMG_W - 1) ? 0.f : cdv;
  float dr  = (gw == 0) ? 0.f : dv;
  float cdr = (gw == 0) ? 0.f : cdv;
  float cfd = cdl * cdr;                                      // cgx_from_ds
  float height = (cdl * dl + cdr * dr) * rcpf_(cdl + cdr + EPSV);
  float gfd = (dr - dl) * 0.5f * rcpf_(height + EPSV);        // gx_from_ds
  float den = fmaf(wpc, cgv, cfd);                            // wp*cgx + cfd
  float num = fmaf(wpc * cgv, gxv, cfd * gfd);
  Pv = den * inv_wp1;
  Vv = num * inv_wp1;
}

// Per-thread staging-task geometry (loop-invariant).
struct TaskGeo {
  int goff;      // within-plane element offset (clamped, even)
  int gc0;       // true global col of element 0
  float m0, m1;  // in-bounds masks
  int wb;        // LDS byte offset of the f4 {P0,V0,P1,V1} write
};

__device__ __forceinline__ TaskGeo make_geo(int inner, int h0, int w0) {
  TaskGeo G;
  const int R = inner / 12;                  // 0..19
  const int hq = inner - R * 12;             // 0..11
  const int gh = h0 + R - 2;
  const int ghc = min(max(gh, 0), IMG_H - 1);
  const int g0 = w0 - 4 + 2 * hq;
  const int g0c = min(max(g0, 0), IMG_W - 2);    // even => 8B aligned
  G.goff = ghc * IMG_W + g0c;
  G.gc0 = g0;
  const bool rowv = (unsigned)gh < (unsigned)IMG_H;
  G.m0 = (rowv & ((unsigned)g0 < (unsigned)IMG_W)) ? 1.f : 0.f;
  G.m1 = (rowv & ((unsigned)(g0 + 1) < (unsigned)IMG_W)) ? 1.f : 0.f;
  G.wb = R * RSB + hq * 16;
  return G;
}

// ---------------------------------------------------------------------------
// Fused kernel: output-split + 4-channel phases.
//
// R11 post-mortem: packed math halved VALU busy (88->54us) but dur stuck at
// 180us; VGPR_Count=48 with 64 live accumulator floats => accumulators in
// AGPRs, unified regs ~112 => hard cap 4 waves/SIMD => the immovable ~39%
// occupancy of every fused variant; too few uncorrelated waves to cover
// load/LDS latency (per-wave issue duty ~40%, 4 x 0.40 < 2-issue saturation).
// This version:
//  - OUTPUT-SPLIT: 2 threads/pixel, 16 outputs each: acc = 16 f2 = 32 regs
//    (halved). Depthwise conv duplicated per pixel-pair (25 pk-FMA, cheap).
//    Target ~6 waves/SIMD.
//  - 4 CHANNELS PER PHASE (8 barriers total): staging 960 tasks/512 thr;
//    prefetch (8 f2) issued after the barrier with a 4-channel conv+acc
//    (~660+ cyc) underneath - 3x R11's latency cover.
//  - s_setprio(1) around conv+acc (stager/non-stager role diversity).
// LDS 30,720 B (2 sets x 4 channel buffers).
// ---------------------------------------------------------------------------
__global__ __launch_bounds__(NT, 5) void fused_kernel(
    const float* __restrict__ dp, const float* __restrict__ cdp,
    const float* __restrict__ gxp, const float* __restrict__ cgxp,
    const float* __restrict__ ws, const float* __restrict__ bias,
    float* __restrict__ out) {
  __shared__ __align__(16) char shb[2 * CHPH * BUFB];  // 30,720 B

  const int t = threadIdx.x;

  // XCD-aware swizzle: 2048 blocks; image k -> XCD k.
  const int wg = blockIdx.x;
  const int virt = (wg & 7) * (NBLK / 8) + (wg >> 3);
  const int b = virt >> 8;                       // /256 tiles
  const int tile = virt & 255;
  const int tx = tile & 15, ty = tile >> 4;      // 16 x 16 tile grid
  const int w0 = tx * TW, h0 = ty * TH;

  const float Ssw = ws[1856], Scw = ws[1857];
  const float epsS = EPSV * Ssw;
  const float oscale = rcpf_(Ssw) * rcpf_(Scw);

  // ---- staging tasks: phase has 960; thread t does t and t+512 ----
  const int c40 = t / NTASK;                     // 0..2 (channel-in-phase)
  const TaskGeo G0 = make_geo(t - c40 * NTASK, h0, w0);
  const bool act1 = t < TPH - NT;                // t < 448
  const int tk1 = min(t + NT, TPH - 1);
  const int c41 = tk1 / NTASK;                   // 2..3
  const TaskGeo G1 = make_geo(tk1 - c41 * NTASK, h0, w0);

  // ---- conv geometry: pixel t>>1, output half t&1 ----
  const int p = t >> 1;
  const int og = t & 1;
  const int x = p & 15, y = p >> 4;
  const int cvb = y * RSB + (x + 2) * 8;
  const int pixoff = (h0 + y) * IMG_W + (w0 + x);
  const int planebase = b * NC * PLANE;

  f2 accDN[16];
  #pragma unroll
  for (int o = 0; o < 16; ++o) accDN[o] = f2{0.f, 0.f};

  // prologue: load phase-0 inputs for both tasks
  f2 d0, c0, g0v, x0, d1, c1, g1v, x1;
  {
    const int p0 = planebase + c40 * PLANE + G0.goff;
    d0 = *(const f2*)(dp + p0);  c0 = *(const f2*)(cdp + p0);
    g0v = *(const f2*)(gxp + p0); x0 = *(const f2*)(cgxp + p0);
    if (act1) {
      const int p1 = planebase + c41 * PLANE + G1.goff;
      d1 = *(const f2*)(dp + p1);  c1 = *(const f2*)(cdp + p1);
      g1v = *(const f2*)(gxp + p1); x1 = *(const f2*)(cgxp + p1);
    }
  }

  #pragma unroll 1
  for (int ph = 0; ph < NC / CHPH; ++ph) {
    const int cb = ph * CHPH;
    char* bset = shb + (ph & 1) * CHPH * BUFB;

    // stage task 0 (all threads)
    {
      const float wpc = ws[cb + c40];
      const float inv_wp1 = rcpf_(wpc + 1.0f);
      float P0, V0, P1, V1;
      pointwise_pv(d0[0], c0[0] * G0.m0, g0v[0], x0[0] * G0.m0, G0.gc0,
                   wpc, inv_wp1, P0, V0);
      pointwise_pv(d0[1], c0[1] * G0.m1, g0v[1], x0[1] * G0.m1, G0.gc0 + 1,
                   wpc, inv_wp1, P1, V1);
      f4 w; w[0] = P0; w[1] = V0; w[2] = P1; w[3] = V1;
      *(f4*)(bset + c40 * BUFB + G0.wb) = w;
    }
    // stage task 1 (t < 448)
    if (act1) {
      const float wpc = ws[cb + c41];
      const float inv_wp1 = rcpf_(wpc + 1.0f);
      float P0, V0, P1, V1;
      pointwise_pv(d1[0], c1[0] * G1.m0, g1v[0], x1[0] * G1.m0, G1.gc0,
                   wpc, inv_wp1, P0, V0);
      pointwise_pv(d1[1], c1[1] * G1.m1, g1v[1], x1[1] * G1.m1, G1.gc0 + 1,
                   wpc, inv_wp1, P1, V1);
      f4 w; w[0] = P0; w[1] = V0; w[2] = P1; w[3] = V1;
      *(f4*)(bset + c41 * BUFB + G1.wb) = w;
    }

    __syncthreads();  // phase ph staged (set ph&1 complete)

    // prefetch next phase AFTER the barrier: 8 f2 loads fly over the
    // 4-channel conv+acc (~660+ cyc); their wait lands at next stage.
    if (ph + 1 < NC / CHPH) {
      const int pb0 = planebase + (cb + CHPH + c40) * PLANE + G0.goff;
      d0 = *(const f2*)(dp + pb0);  c0 = *(const f2*)(cdp + pb0);
      g0v = *(const f2*)(gxp + pb0); x0 = *(const f2*)(cgxp + pb0);
      if (act1) {
        const int pb1 = planebase + (cb + CHPH + c41) * PLANE + G1.goff;
        d1 = *(const f2*)(dp + pb1);  c1 = *(const f2*)(cdp + pb1);
        g1v = *(const f2*)(gxp + pb1); x1 = *(const f2*)(cgxp + pb1);
      }
    }

    // conv + acc for 4 channels (both pixel-threads compute conv; each
    // accumulates its own 16-output half)
    __builtin_amdgcn_s_setprio(1);
    #pragma unroll
    for (int cc = 0; cc < CHPH; ++cc) {
      const char* bp = bset + cc * BUFB + cvb;
      const float* swc = ws + 32 + (cb + cc) * 25;
      f2 dn = f2{0.f, 0.f};
      #pragma unroll
      for (int kr = 0; kr < 5; ++kr) {
        #pragma unroll
        for (int kc = 0; kc < 5; ++kc) {
          const f2 pv = *(const f2*)(bp + kr * RSB + kc * 8);
          dn += pv * swc[kr * 5 + kc];           // v_pk_fma_f32
        }
      }
      const float* cwc = ws + 832 + (cb + cc) * NO + og * 16;
      #pragma unroll
      for (int o = 0; o < 16; ++o)
        accDN[o] += dn * cwc[o];                 // v_pk_fma_f32
    }
    __builtin_amdgcn_s_setprio(0);
    // hazard: next phase writes the OTHER buffer set; writes to THIS set
    // recur two phases later, ordered by the intervening phase's barrier.
  }

  // epilogue: folded normalization + store (each thread: 16 outputs)
  //   gx[o]  = N/(D + EPS*Ssw) + bias[o];  cgx[o] = D/(Ssw*Scw)
  const int ob = b * NO * PLANE + pixoff;
  #pragma unroll
  for (int o = 0; o < 16; ++o) {
    const int oo = og * 16 + o;
    const float D = accDN[o][0], N = accDN[o][1];
    out[ob + oo * PLANE] = fmaf(N, rcpf_(D + epsS), bias[oo]);
    out[HALF + ob + oo * PLANE] = D * oscale;
  }
}

extern "C" void kernel_launch(void* const* d_in, const int* in_sizes, int n_in,
                              void* d_out, int out_size, void* d_ws, size_t ws_size,
                              hipStream_t stream) {
  const float* dp   = (const float*)d_in[0];
  const float* cdp  = (const float*)d_in[1];
  const float* gxp  = (const float*)d_in[2];
  const float* cgxp = (const float*)d_in[3];
  const float* wp   = (const float*)d_in[4];
  const float* sw   = (const float*)d_in[5];
  const float* cw   = (const float*)d_in[6];
  const float* bias = (const float*)d_in[7];
  float* out = (float*)d_out;
  float* ws  = (float*)d_ws;

  weights_kernel<<<1, 256, 0, stream>>>(wp, sw, cw, ws);
  fused_kernel<<<NBLK, NT, 0, stream>>>(dp, cdp, gxp, cgxp, ws, bias, out);
}

// Round 13
// 399.606 us; speedup vs baseline: 1.5577x; 1.5577x over previous
//
#include <hip/hip_runtime.h>
#include <math.h>

// Problem constants (reference: B=8, C=32, O=32, H=256, W=256, K=5, pad=2)
constexpr int IMG_H = 256;
constexpr int IMG_W = 256;
constexpr int NB = 8;
constexpr int NC = 32;
constexpr int NO = 32;
constexpr int PLANE = IMG_H * IMG_W;          // 65536
constexpr int HALF = NB * NC * PLANE;         // 16,777,216 floats (64 MB)

// Fused tiling (R5 measured-best geometry): block = one (b, 16x32 tile),
// thread = one pixel. One channel per barrier phase, 2 LDS buffers,
// prefetch of channel c+1 issued BEFORE the barrier (R5 position: the
// barrier's vmcnt drain overlaps the wait for sibling waves, so conv runs
// stall-free after it — moving the prefetch after the barrier cost +14-30us
// in R7/R8/R10/R11).
constexpr int TW = 16;                        // tile width
constexpr int TH = 32;                        // tile height
constexpr int NT = TW * TH;                   // 512 threads
constexpr int RR = TH + 4;                    // 36 region rows
constexpr int RC = 24;                        // stored cols [w0-4, w0+20)
constexpr int RSB = RC * 8;                   // 192 B row stride ({P,V} f2/px)
constexpr int BUFB = RR * RSB;                // 6912 B per channel buffer
constexpr int NTASK = RR * 12;                // 432 staging tasks (2 px each)
constexpr int TILES = (IMG_W / TW) * (IMG_H / TH);  // 128 tiles per image

#define EPSV 1e-20f

typedef float f4 __attribute__((ext_vector_type(4)));
typedef float f2 __attribute__((ext_vector_type(2)));

__device__ __forceinline__ float rcpf_(float x) { return __builtin_amdgcn_rcpf(x); }
__device__ __forceinline__ float softplusf_(float x) {
  return fmaxf(x, 0.0f) + log1pf(expf(-fabsf(x)));
}

// ws layout (floats): [0..31] wp, [32..831] sw (c-major, 25/ch),
// [832..1855] cwT[c][o] (transposed), [1856] sum(sw), [1857] sum(cw)
__global__ void weights_kernel(const float* __restrict__ wp_raw,
                               const float* __restrict__ sw_raw,
                               const float* __restrict__ cw_raw,
                               float* __restrict__ ws) {
  __shared__ float red[256];
  const int t = threadIdx.x;
  if (t < 32) ws[t] = softplusf_(wp_raw[t]);
  float ssum = 0.f;
  for (int i = t; i < NC * 25; i += 256) {
    float v = softplusf_(sw_raw[i]);
    ws[32 + i] = v;
    ssum += v;
  }
  float csum = 0.f;
  for (int i = t; i < NO * NC; i += 256) {
    float v = softplusf_(cw_raw[i]);
    int o = i >> 5, c = i & 31;
    ws[832 + c * NO + o] = v;  // transposed: [c][o]
    csum += v;
  }
  red[t] = ssum; __syncthreads();
  for (int off = 128; off; off >>= 1) { if (t < off) red[t] += red[t + off]; __syncthreads(); }
  const float S_sw = red[0];
  __syncthreads();
  red[t] = csum; __syncthreads();
  for (int off = 128; off; off >>= 1) { if (t < off) red[t] += red[t + off]; __syncthreads(); }
  if (t == 0) { ws[1856] = S_sw; ws[1857] = red[0]; }
}

// Pointwise gradient-propagation math. Requires cdv/cgv pre-zeroed for
// OOB pixels (then Pv = Vv = 0 algebraically, no NaN).
// P = den*inv_wp1; V = num*inv_wp1 (den/(den+eps) == 1 to fp32 unless
// den < 1e-13, where |num| <= den*O(1); den=0 => num=0 => V=0). Verified
// in R11: absmax unchanged (2.44e-4). All rcp args >= EPSV (R9 lesson).
__device__ __forceinline__ void pointwise_pv(
    float dv, float cdv, float gxv, float cgv, int gw,
    float wpc, float inv_wp1, float& Pv, float& Vv) {
  float dl  = (gw == IMG_W - 1) ? 0.f : dv;
  float cdl = (gw == IMG_W - 1) ? 0.f : cdv;
  float dr  = (gw == 0) ? 0.f : dv;
  float cdr = (gw == 0) ? 0.f : cdv;
  float cfd = cdl * cdr;                                      // cgx_from_ds
  float height = (cdl * dl + cdr * dr) * rcpf_(cdl + cdr + EPSV);
  float gfd = (dr - dl) * 0.5f * rcpf_(height + EPSV);        // gx_from_ds
  float den = fmaf(wpc, cgv, cfd);                            // wp*cgx + cfd
  float num = fmaf(wpc * cgv, gxv, cfd * gfd);
  Pv = den * inv_wp1;
  Vv = num * inv_wp1;
}

// ---------------------------------------------------------------------------
// Fused kernel = R5's measured-best structure (167us) + R11's counter-proven
// packed-f2 math (halved VALU busy 88->54us). ONE variable vs R5.
//
// R12 lesson (repeated from R2): launch_bounds must leave >=128 unified regs
// or the accumulators spill to scratch (+364MB WRITE). bounds(512,4) here.
// Accumulators live in AGPRs (VGPR_Count ~48 + 64 acc): accepted — R11
// showed the acc FMA stream at 32 pk-FMA/channel is cheap enough.
// ---------------------------------------------------------------------------
__global__ __launch_bounds__(NT, 4) void fused_kernel(
    const float* __restrict__ dp, const float* __restrict__ cdp,
    const float* __restrict__ gxp, const float* __restrict__ cgxp,
    const float* __restrict__ ws, const float* __restrict__ bias,
    float* __restrict__ out) {
  __shared__ __align__(16) char shb[2 * BUFB];  // 13,824 B

  const int t = threadIdx.x;

  // XCD-aware swizzle: 1024 blocks; image k -> XCD k.
  const int wg = blockIdx.x;
  const int virt = (wg & 7) * TILES + (wg >> 3);
  const int b = virt >> 7;                       // /128 tiles
  const int tile = virt & (TILES - 1);
  const int tx = tile & 15, ty = tile >> 4;      // 16 x 8 tile grid
  const int w0 = tx * TW, h0 = ty * TH;

  const float Ssw = ws[1856], Scw = ws[1857];
  const float epsS = EPSV * Ssw;
  const float oscale = rcpf_(Ssw) * rcpf_(Scw);

  // ---- staging geometry: 432 tasks (36 rows x 12 col-pairs), t<432 ----
  const bool sact = t < NTASK;
  const int task = min(t, NTASK - 1);
  const int R = task / 12;
  const int hq = task - R * 12;
  const int gh = h0 + R - 2;
  const int ghc = min(max(gh, 0), IMG_H - 1);
  const int g0 = w0 - 4 + 2 * hq;
  const int g0c = min(max(g0, 0), IMG_W - 2);    // even => 8B aligned
  const int goff = ghc * IMG_W + g0c;
  const bool rowv = (unsigned)gh < (unsigned)IMG_H;
  const float m0 = (rowv & ((unsigned)g0 < (unsigned)IMG_W)) ? 1.f : 0.f;
  const float m1 = (rowv & ((unsigned)(g0 + 1) < (unsigned)IMG_W)) ? 1.f : 0.f;
  const int wb = R * RSB + hq * 16;              // 16B-aligned f4 write

  // ---- conv geometry ----
  const int x = t & (TW - 1);
  const int r = t >> 4;                          // 0..31
  const int cvb = r * RSB + (x + 2) * 8;         // tap(0,0) byte
  const int pixoff = (h0 + r) * IMG_W + (w0 + x);
  const int planebase = b * NC * PLANE;

  // packed accumulators: accDN[o] = {sum cw*D, sum cw*N}
  f2 accDN[32];
  #pragma unroll
  for (int o = 0; o < 32; ++o) accDN[o] = f2{0.f, 0.f};

  // prologue: load channel 0
  f2 vd, vc, vg, vx;
  if (sact) {
    vd = *(const f2*)(dp + planebase + goff);
    vc = *(const f2*)(cdp + planebase + goff);
    vg = *(const f2*)(gxp + planebase + goff);
    vx = *(const f2*)(cgxp + planebase + goff);
  }

  #pragma unroll 1
  for (int c = 0; c < NC; ++c) {
    char* buf = shb + (c & 1) * BUFB;
    const float wpc = ws[c];
    const float inv_wp1 = rcpf_(wpc + 1.0f);

    // stage: pointwise 2 px -> one f4 {P0,V0,P1,V1}
    if (sact) {
      float P0, V0, P1, V1;
      pointwise_pv(vd[0], vc[0] * m0, vg[0], vx[0] * m0, g0,
                   wpc, inv_wp1, P0, V0);
      pointwise_pv(vd[1], vc[1] * m1, vg[1], vx[1] * m1, g0 + 1,
                   wpc, inv_wp1, P1, V1);
      f4 w; w[0] = P0; w[1] = V0; w[2] = P1; w[3] = V1;
      *(f4*)(buf + wb) = w;
    }

    // prefetch channel c+1 BEFORE the barrier (R5 position): the barrier's
    // vmcnt drain overlaps the wait for sibling waves; conv then runs with
    // data already in registers. (Measured: moving this after the barrier
    // cost +14-30us across R7/R8/R10/R11.)
    if ((c + 1 < NC) & sact) {
      const int pb = planebase + (c + 1) * PLANE + goff;
      vd = *(const f2*)(dp + pb);
      vc = *(const f2*)(cdp + pb);
      vg = *(const f2*)(gxp + pb);
      vx = *(const f2*)(cgxp + pb);
    }

    __syncthreads();  // channel c staged (+ prefetch drained during wait)

    // depthwise 5x5, packed: dn = {D_c, N_c}  (25 x v_pk_fma_f32)
    const char* bp = buf + cvb;
    const float* swc = ws + 32 + c * 25;
    f2 dn = f2{0.f, 0.f};
    #pragma unroll
    for (int kr = 0; kr < 5; ++kr) {
      #pragma unroll
      for (int kc = 0; kc < 5; ++kc) {
        const f2 pv = *(const f2*)(bp + kr * RSB + kc * 8);
        dn += pv * swc[kr * 5 + kc];             // v_pk_fma_f32
      }
    }

    // rank-1 update, packed (static indices; 32 x v_pk_fma_f32)
    const float* cwc = ws + 832 + c * NO;
    #pragma unroll
    for (int o = 0; o < 32; ++o)
      accDN[o] += dn * cwc[o];

    // next iteration stages the OTHER buffer; writes to THIS buffer occur
    // two iterations later, fenced by the next iteration's barrier.
  }

  // epilogue: folded normalization + coalesced store
  //   gx[o]  = N/(D + EPS*Ssw) + bias[o];  cgx[o] = D/(Ssw*Scw)
  const int ob = b * NO * PLANE + pixoff;
  #pragma unroll
  for (int o = 0; o < 32; ++o) {
    const float D = accDN[o][0], N = accDN[o][1];
    out[ob + o * PLANE] = fmaf(N, rcpf_(D + epsS), bias[o]);
    out[HALF + ob + o * PLANE] = D * oscale;
  }
}

extern "C" void kernel_launch(void* const* d_in, const int* in_sizes, int n_in,
                              void* d_out, int out_size, void* d_ws, size_t ws_size,
                              hipStream_t stream) {
  const float* dp   = (const float*)d_in[0];
  const float* cdp  = (const float*)d_in[1];
  const float* gxp  = (const float*)d_in[2];
  const float* cgxp = (const float*)d_in[3];
  const float* wp   = (const float*)d_in[4];
  const float* sw   = (const float*)d_in[5];
  const float* cw   = (const float*)d_in[6];
  const float* bias = (const float*)d_in[7];
  float* out = (float*)d_out;
  float* ws  = (float*)d_ws;

  weights_kernel<<<1, 256, 0, stream>>>(wp, sw, cw, ws);
  fused_kernel<<<TILES * NB, NT, 0, stream>>>(dp, cdp, gxp, cgxp, ws, bias,
                                              out);
}